// Round 12
// baseline (1197.258 us; speedup 1.0000x reference)
//
#include <hip/hip_runtime.h>
#include <math.h>

// ---- problem constants ----
#define S_LEN  2048
#define DMODEL 1024
#define NHEAD  16
#define BATCH  4
#define NROWS  (BATCH*S_LEN)   // 8192
#define DFF    4096
#define QKV_LD 3072            // fused q|k|v row stride

typedef __attribute__((ext_vector_type(4))) unsigned short us4;
typedef __attribute__((ext_vector_type(8))) unsigned short us8;
typedef __attribute__((ext_vector_type(8))) __bf16 bf16x8;
typedef __attribute__((ext_vector_type(4))) float f32x4;

#if __has_builtin(__builtin_amdgcn_exp2f)
#define EXP2(x) __builtin_amdgcn_exp2f(x)
#else
#define EXP2(x) exp2f(x)
#endif
#if __has_builtin(__builtin_amdgcn_rcpf)
#define RCP(x) __builtin_amdgcn_rcpf(x)
#else
#define RCP(x) (1.0f/(x))
#endif

static __device__ __forceinline__ unsigned short f2bf(float f) {
  __bf16 b = (__bf16)f;                       // HW RNE convert on gfx950
  return __builtin_bit_cast(unsigned short, b);
}
#define GLD16(gp, lp) __builtin_amdgcn_global_load_lds( \
    (const __attribute__((address_space(1))) unsigned int*)(gp), \
    (__attribute__((address_space(3))) unsigned int*)(lp), 16, 0, 0)

// XCD-aware bijective block swizzle (requires gridDim.x % 8 == 0)
static __device__ __forceinline__ int xcd_swz(int bid, int nwg) {
  int q = nwg >> 3;
  return (bid & 7) * q + (bid >> 3);
}

// ---------------- LayerNorm: fp32 in -> bf16 out ----------------
__global__ __launch_bounds__(256) void ln_kernel(
    const float* __restrict__ x, const float* __restrict__ scale,
    const float* __restrict__ shift, unsigned short* __restrict__ out)
{
  const int row = blockIdx.x, tid = threadIdx.x;
  const int lane = tid & 63, wave = tid >> 6;
  const float* xr = x + (size_t)row * DMODEL;
  f32x4 v = *(const f32x4*)&xr[tid * 4];
  float s  = v[0]+v[1]+v[2]+v[3];
  float s2 = v[0]*v[0]+v[1]*v[1]+v[2]*v[2]+v[3]*v[3];
  #pragma unroll
  for (int m = 1; m < 64; m <<= 1) { s += __shfl_xor(s, m); s2 += __shfl_xor(s2, m); }
  __shared__ float red[8];
  if (lane == 0) { red[wave] = s; red[4 + wave] = s2; }
  __syncthreads();
  s  = red[0]+red[1]+red[2]+red[3];
  s2 = red[4]+red[5]+red[6]+red[7];
  float mean = s * (1.0f/DMODEL);
  float var  = s2 * (1.0f/DMODEL) - mean*mean;
  float rstd = rsqrtf(var + 1e-5f);
  us4 o;
  #pragma unroll
  for (int j = 0; j < 4; j++) {
    float val = (v[j]-mean)*rstd*scale[tid*4+j] + shift[tid*4+j];
    o[j] = f2bf(val);
  }
  *(us4*)&out[(size_t)row*DMODEL + tid*4] = o;
}

// ------- merged weight convert+transpose: all 6 weights in one launch -------
__global__ __launch_bounds__(256) void wtrans_all(
    const float* __restrict__ Wq, const float* __restrict__ Wk,
    const float* __restrict__ Wv, const float* __restrict__ Wo,
    const float* __restrict__ W1, const float* __restrict__ W2,
    unsigned short* __restrict__ wqkvt, unsigned short* __restrict__ wot,
    unsigned short* __restrict__ w1t, unsigned short* __restrict__ w2t,
    float sclq)
{
  __shared__ unsigned short tile[64][72];
  const int bid = blockIdx.x, tid = threadIdx.x;
  const float* W; unsigned short* Wt; int K, N, sub; float scl = 1.0f;
  if (bid < 1024) {
    int wsel = bid >> 8; sub = bid & 255; K = 1024; N = 1024;
    W  = (wsel == 0) ? Wq : (wsel == 1) ? Wk : (wsel == 2) ? Wv : Wo;
    Wt = (wsel == 0) ? wqkvt : (wsel == 1) ? wqkvt + 1024*1024
       : (wsel == 2) ? wqkvt + 2048*1024 : wot;
    if (wsel == 0) scl = sclq;
  } else if (bid < 2048) { sub = bid - 1024; K = 1024; N = 4096; W = W1; Wt = w1t; }
  else                   { sub = bid - 2048; K = 4096; N = 1024; W = W2; Wt = w2t; }
  const int nbn = N >> 6;
  const int kt = sub / nbn, nt = sub % nbn;
  int r = tid >> 2, c0 = (tid & 3) << 4;
  const float* src = W + (size_t)(kt*64 + r)*N + nt*64 + c0;
  #pragma unroll
  for (int j = 0; j < 16; j += 4) {
    f32x4 f = *(const f32x4*)&src[j];
    tile[r][c0+j+0] = f2bf(f[0]*scl); tile[r][c0+j+1] = f2bf(f[1]*scl);
    tile[r][c0+j+2] = f2bf(f[2]*scl); tile[r][c0+j+3] = f2bf(f[3]*scl);
  }
  __syncthreads();
  int n = tid >> 2, k0 = (tid & 3) << 4;
  us8 o0, o1;
  #pragma unroll
  for (int j = 0; j < 8; j++) { o0[j] = tile[k0+j][n]; o1[j] = tile[k0+8+j][n]; }
  unsigned short* dst = Wt + (size_t)(nt*64 + n)*K + kt*64 + k0;
  *(us8*)&dst[0] = o0;
  *(us8*)&dst[8] = o1;
}

// ------- V transpose: v rows [B*S][QKV_LD] (v section) -> vt[(b*H+h)*64+d][S] -------
__global__ __launch_bounds__(256) void vtrans(
    const unsigned short* __restrict__ v, unsigned short* __restrict__ vt)
{
  __shared__ unsigned short tile[64][72];
  const int tid = threadIdx.x;
  const int bh = blockIdx.x >> 5, st = blockIdx.x & 31;
  const int b = bh >> 4, h = bh & 15;
  int r = tid >> 2, c0 = (tid & 3) << 4;
  const unsigned short* src = v + (size_t)(b*S_LEN + st*64 + r)*QKV_LD + h*64 + c0;
  *(us8*)&tile[r][c0]   = *(const us8*)&src[0];
  *(us8*)&tile[r][c0+8] = *(const us8*)&src[8];
  __syncthreads();
  int d = tid >> 2, s0 = (tid & 3) << 4;
  us8 o0, o1;
  #pragma unroll
  for (int j = 0; j < 8; j++) { o0[j] = tile[s0+j][d]; o1[j] = tile[s0+8+j][d]; }
  unsigned short* dst = vt + (size_t)(bh*64 + d)*S_LEN + st*64 + s0;
  *(us8*)&dst[0] = o0;
  *(us8*)&dst[8] = o1;
}

// ------- 256x256 BK=32 pipelined GEMM (QKV / FFN1) -------
// 8 waves (2Mx4N), per-wave 128x64. LDS = 2dbuf x (256x32 A + 256x32 B) x 2B = 64KB
// -> 2 blocks/CU -> 4 waves/SIMD (cross-block barrier overlap). 2 phases/K-tile.
// Swizzle: 16B chunk ^= row&3 on BOTH global source and LDS read (involution).
// vmcnt(2) at tile top: outstanding = A(t)2 + B(t+1)2, B(t) older than A(t).
template<bool BIAS, bool GELU_>
__global__ __launch_bounds__(512, 4) void gemm256b32(
    const unsigned short* __restrict__ A, const unsigned short* __restrict__ Bt,
    unsigned short* __restrict__ Cout, const float* __restrict__ bias,
    int M, int N, int K)
{
  __shared__ unsigned short sA[2][256*32];
  __shared__ unsigned short sB[2][256*32];
  const int tid = threadIdx.x;
  const int wave = tid >> 6, lane = tid & 63;
  const int wm = wave >> 2, wn = wave & 3;
  const int l15 = lane & 15, g = lane >> 4;
  const int row_l = lane >> 2;                    // 0..15 within a wave's 16-row unit
  const int csrc = ((lane & 3) ^ (row_l & 3)) * 8;  // pre-swizzled source chunk (elems)
  const int nbn = N >> 8;
  const int bid = xcd_swz(blockIdx.x, gridDim.x);
  const int bm = bid / nbn, bn = bid % nbn;
  const unsigned short* gA = A  + (size_t)(bm*256)*K;
  const unsigned short* gB = Bt + (size_t)(bn*256)*K;
  const int NT = K >> 5;

  f32x4 acc[8][4] = {};

  // one GLD16/half stages 128 rows x 32 cols; wave covers rows wave*16..+15
#define STA32(buf, kb) do { \
    GLD16(gA + (size_t)(      wave*16 + row_l)*K + (kb) + csrc, &sA[buf][(      wave*16)*32]); \
    GLD16(gA + (size_t)(128 + wave*16 + row_l)*K + (kb) + csrc, &sA[buf][(128 + wave*16)*32]); \
  } while (0)
#define STB32(buf, kb) do { \
    GLD16(gB + (size_t)(      wave*16 + row_l)*K + (kb) + csrc, &sB[buf][(      wave*16)*32]); \
    GLD16(gB + (size_t)(128 + wave*16 + row_l)*K + (kb) + csrc, &sB[buf][(128 + wave*16)*32]); \
  } while (0)
  // read global k-chunk g from swizzled LDS: chunk = g ^ (row&3); row&3 == l15&3
#define RDA32(m) (*(const bf16x8*)&cA[(wm*128 + (m)*16 + l15)*32 + (((g)^(l15&3))<<3)])
#define RDB32(n) (*(const bf16x8*)&cB[(wn*64  + (n)*16 + l15)*32 + (((g)^(l15&3))<<3)])
#define MF32(mbase) do { \
    __builtin_amdgcn_s_setprio(1); \
    _Pragma("unroll") for (int mm_ = 0; mm_ < 4; mm_++) \
    _Pragma("unroll") for (int n_ = 0; n_ < 4; n_++) \
      acc[(mbase)+mm_][n_] = __builtin_amdgcn_mfma_f32_16x16x32_bf16( \
          af[mm_], bfr[n_], acc[(mbase)+mm_][n_], 0, 0, 0); \
    __builtin_amdgcn_s_setprio(0); \
  } while (0)

  // prologue: B(0), A(0), B(1) -> 6 GLD16/thread outstanding
  STB32(0, 0);
  STA32(0, 0);
  STB32(1, 32);

  for (int t = 0; t < NT; ++t) {
    const int c = t & 1;
    const unsigned short* cA = sA[c];
    const unsigned short* cB = sB[c];
    bf16x8 af[4], bfr[4];

    if (t < NT - 1) asm volatile("s_waitcnt vmcnt(2)" ::: "memory");
    else            asm volatile("s_waitcnt vmcnt(0)" ::: "memory");
    __builtin_amdgcn_s_barrier();
    __builtin_amdgcn_sched_barrier(0);

    // ---- ph1: B reg-cache + A m0..3 + stage A(t+1) into other buf ----
    #pragma unroll
    for (int n = 0; n < 4; n++) bfr[n] = RDB32(n);
    af[0] = RDA32(0); af[1] = RDA32(1); af[2] = RDA32(2); af[3] = RDA32(3);
    if (t + 1 < NT) STA32(c ^ 1, (t + 1) * 32);
    MF32(0);
    __builtin_amdgcn_s_barrier();        // B-region recycle gate (all B reads done)
    // ---- ph2: A m4..7 + stage B(t+2) into current buf's B ----
    af[0] = RDA32(4); af[1] = RDA32(5); af[2] = RDA32(6); af[3] = RDA32(7);
    if (t + 2 < NT) STB32(c, (t + 2) * 32);
    MF32(4);
  }

  // epilogue: row = bm*256 + wm*128 + m*16 + g*4 + r ; col = bn*256 + wn*64 + n*16 + l15
  #pragma unroll
  for (int m = 0; m < 8; m++) {
    #pragma unroll
    for (int r = 0; r < 4; r++) {
      int grow = bm*256 + wm*128 + m*16 + g*4 + r;
      #pragma unroll
      for (int n = 0; n < 4; n++) {
        int gcol = bn*256 + wn*64 + n*16 + l15;
        float v = acc[m][n][r];
        if (BIAS) v += bias[gcol];
        if (GELU_) {
          float xx = v;
          float u = 0.7978845608f*(xx + 0.044715f*xx*xx*xx);
          float e = EXP2(u * 2.88539008f);
          float th = 1.0f - 2.0f*RCP(e + 1.0f);
          v = 0.5f*xx*(1.0f + th);
        }
        Cout[(size_t)grow*N + gcol] = f2bf(v);
      }
    }
  }
#undef STA32
#undef STB32
#undef RDA32
#undef RDB32
#undef MF32
}

// ------- 128x256 pipelined GEMM (Wo / FFN2): 8 waves (2Mx4N), per-wave 64x64 -------
template<bool BIAS, bool GELU_, bool RESID, bool OUTF32>
__global__ __launch_bounds__(512, 2) void gemm128(
    const unsigned short* __restrict__ A, const unsigned short* __restrict__ Bt,
    void* Cout, const float* __restrict__ bias, const float* resid,
    int M, int N, int K)
{
  __shared__ unsigned short sA[2][128*64];
  __shared__ unsigned short sB[2][256*64];
  const int tid = threadIdx.x;
  const int wave = tid >> 6, lane = tid & 63;
  const int wm = wave >> 2, wn = wave & 3;
  const int l15 = lane & 15, g = lane >> 4, x7 = lane & 7, r8 = lane >> 3;
  const int srcc = (x7 ^ r8) << 3;
  const int nbn = N >> 8;
  const int bid = xcd_swz(blockIdx.x, gridDim.x);
  const int bm = bid / nbn, bn = bid % nbn;
  const unsigned short* gA = A  + (size_t)(bm*128)*K;
  const unsigned short* gB = Bt + (size_t)(bn*256)*K;
  const int NT = K >> 6;

  f32x4 acc[4][4] = {};

#define STAGEA1(buf, kb) do { \
    _Pragma("unroll") \
    for (int j_ = 0; j_ < 2; j_++) \
      GLD16(gA + (size_t)(j_*64 + wave*8 + r8)*K + (kb) + srcc, \
            &sA[buf][(j_*64 + wave*8)*64]); \
  } while (0)
#define STAGEB1(buf, kb) do { \
    _Pragma("unroll") \
    for (int j_ = 0; j_ < 4; j_++) \
      GLD16(gB + (size_t)(j_*64 + wave*8 + r8)*K + (kb) + srcc, \
            &sB[buf][(j_*64 + wave*8)*64]); \
  } while (0)
#define RDA1(m, kk) (*(const bf16x8*)&cA[(wm*64 + (m)*16 + l15)*64 + ((((kk)*4+g)^x7)<<3)])
#define RDB1(n, kk) (*(const bf16x8*)&cB[(wn*64 + (n)*16 + l15)*64 + ((((kk)*4+g)^x7)<<3)])
#define PH1(p) do { \
    __builtin_amdgcn_s_setprio(1); \
    _Pragma("unroll") for (int mm_ = 0; mm_ < 2; mm_++) \
    _Pragma("unroll") for (int n_ = 0; n_ < 4; n_++) \
    _Pragma("unroll") for (int kk_ = 0; kk_ < 2; kk_++) \
      acc[(p)*2+mm_][n_] = __builtin_amdgcn_mfma_f32_16x16x32_bf16( \
          af[mm_][kk_], bfr[n_][kk_], acc[(p)*2+mm_][n_], 0, 0, 0); \
    __builtin_amdgcn_s_setprio(0); \
  } while (0)

  STAGEB1(0, 0);
  STAGEA1(0, 0);
  STAGEB1(1, 64);

  for (int t = 0; t < NT; ++t) {
    const int c = t & 1;
    const unsigned short* cA = sA[c];
    const unsigned short* cB = sB[c];
    const int kb1 = (t + 1) * 64, kb2 = (t + 2) * 64;
    bf16x8 af[2][2], bfr[4][2];

    if (t < NT - 1) asm volatile("s_waitcnt vmcnt(4)" ::: "memory");
    else            asm volatile("s_waitcnt vmcnt(0)" ::: "memory");
    __builtin_amdgcn_s_barrier();
    __builtin_amdgcn_sched_barrier(0);

    // ---- ph1: B reg-cache + A m0,m1 + stage A(t+1) ----
    #pragma unroll
    for (int n = 0; n < 4; n++) { bfr[n][0] = RDB1(n, 0); bfr[n][1] = RDB1(n, 1); }
    af[0][0] = RDA1(0, 0); af[0][1] = RDA1(0, 1);
    af[1][0] = RDA1(1, 0); af[1][1] = RDA1(1, 1);
    if (t + 1 < NT) STAGEA1(c ^ 1, kb1);
    PH1(0);
    __builtin_amdgcn_s_barrier();        // B-region recycle gate (B reads done)
    // ---- ph2: A m2,m3 + stage B(t+2) into current buf ----
    af[0][0] = RDA1(2, 0); af[0][1] = RDA1(2, 1);
    af[1][0] = RDA1(3, 0); af[1][1] = RDA1(3, 1);
    if (t + 2 < NT) STAGEB1(c, kb2);
    PH1(1);
  }

  #pragma unroll
  for (int m = 0; m < 4; m++) {
    #pragma unroll
    for (int r = 0; r < 4; r++) {
      int grow = bm*128 + wm*64 + m*16 + g*4 + r;
      #pragma unroll
      for (int n = 0; n < 4; n++) {
        int gcol = bn*256 + wn*64 + n*16 + l15;
        float v = acc[m][n][r];
        if (BIAS) v += bias[gcol];
        if (GELU_) {
          float xx = v;
          float u = 0.7978845608f*(xx + 0.044715f*xx*xx*xx);
          float e = EXP2(u * 2.88539008f);
          float th = 1.0f - 2.0f*RCP(e + 1.0f);
          v = 0.5f*xx*(1.0f + th);
        }
        if (RESID) v += resid[(size_t)grow*N + gcol];
        if (OUTF32) ((float*)Cout)[(size_t)grow*N + gcol] = v;
        else ((unsigned short*)Cout)[(size_t)grow*N + gcol] = f2bf(v);
      }
    }
  }
#undef STAGEA1
#undef STAGEB1
#undef RDA1
#undef RDB1
#undef PH1
}

// ---------------- causal flash attention (QBLK=128, proven) ----------------
// 8 waves x 16 q-rows. Ones-column MFMA denominator; defer-max; exp2 domain.
__global__ __launch_bounds__(512) void attn_kernel(
    const unsigned short* __restrict__ qb, const unsigned short* __restrict__ kb,
    const unsigned short* __restrict__ vt, unsigned short* __restrict__ ctx)
{
  __shared__ unsigned short sK[2][64*64];
  __shared__ unsigned short sV[2][64*64];
  __shared__ unsigned short sP[8][16*64];
  const int tid = threadIdx.x, wave = tid >> 6, lane = tid & 63;
  const int l15 = lane & 15, g = lane >> 4, x7 = lane & 7;
  const int qt = 15 - (blockIdx.x >> 6);      // heavy-first, QBLK=128
  const int bh = blockIdx.x & 63;
  const int b = bh >> 4, h = bh & 15;
  const int qrow = qt*128 + wave*16;
  const int NTI = 2*qt + 2;

  bf16x8 qf[2];
  {
    const unsigned short* qr = qb + (size_t)(b*S_LEN + qrow + l15) * QKV_LD + h*64;
    qf[0] = *(const bf16x8*)&qr[g*8];
    qf[1] = *(const bf16x8*)&qr[32 + g*8];
  }

  us8 ones_u;
  #pragma unroll
  for (int j = 0; j < 8; j++) ones_u[j] = 0x3F80;
  const bf16x8 ones8 = __builtin_bit_cast(bf16x8, ones_u);

  f32x4 oacc[4] = {};
  f32x4 lacc = {};
  float mrow[4];
  #pragma unroll
  for (int r = 0; r < 4; r++) mrow[r] = -INFINITY;

  const int rrow = lane >> 3;
  const int srcc = (x7 ^ rrow) << 3;
  const unsigned short* kbase = kb + (size_t)(b*S_LEN)*QKV_LD + h*64 + srcc;
  const unsigned short* vbase = vt + (size_t)(bh*64)*S_LEN + srcc;

#define ASTAGE(buf, t) do { \
    const int kv0_ = (t)*64; \
    GLD16(kbase + (size_t)(kv0_ + wave*8 + rrow)*QKV_LD, &sK[buf][wave*8*64]); \
    GLD16(vbase + (size_t)(wave*8 + rrow)*S_LEN + kv0_,  &sV[buf][wave*8*64]); \
  } while(0)

  ASTAGE(0, 0);

  for (int t = 0; t < NTI; ++t) {
    __syncthreads();
    const int cur = t & 1;
    if (t < NTI - 1) ASTAGE(cur ^ 1, t + 1);

    const int kv0 = t*64;
    if (kv0 > qrow + 15) continue;

    f32x4 sacc[4] = {};
    __builtin_amdgcn_s_setprio(1);
    #pragma unroll
    for (int kk = 0; kk < 2; kk++) {
      const int csw = ((kk*4 + g) ^ x7) << 3;
      #pragma unroll
      for (int n = 0; n < 4; n++) {
        bf16x8 kf = *(const bf16x8*)&sK[cur][(n*16 + l15)*64 + csw];
        sacc[n] = __builtin_amdgcn_mfma_f32_16x16x32_bf16(qf[kk], kf, sacc[n], 0, 0, 0);
      }
    }
    __builtin_amdgcn_s_setprio(0);

    float p[4][4], rm[4];
    const bool masked = (kv0 + 63 > qrow);
    #pragma unroll
    for (int r = 0; r < 4; r++) {
      float m_ = -INFINITY;
      #pragma unroll
      for (int n = 0; n < 4; n++) {
        float sc = sacc[n][r];
        if (masked && (kv0 + n*16 + l15) > (qrow + g*4 + r)) sc = -INFINITY;
        p[n][r] = sc;
        m_ = fmaxf(m_, sc);
      }
      rm[r] = m_;
    }
    bool need = (rm[0] > mrow[0] + 8.0f) | (rm[1] > mrow[1] + 8.0f) |
                (rm[2] > mrow[2] + 8.0f) | (rm[3] > mrow[3] + 8.0f);
    if (__any(need)) {
      #pragma unroll
      for (int r = 0; r < 4; r++) {
        float vv = rm[r];
        vv = fmaxf(vv, __shfl_xor(vv, 1));
        vv = fmaxf(vv, __shfl_xor(vv, 2));
        vv = fmaxf(vv, __shfl_xor(vv, 4));
        vv = fmaxf(vv, __shfl_xor(vv, 8));
        float mn = fmaxf(mrow[r], vv);
        float alpha = EXP2(mrow[r] - mn);
        mrow[r] = mn;
        lacc[r] *= alpha;
        #pragma unroll
        for (int nd = 0; nd < 4; nd++) oacc[nd][r] *= alpha;
      }
    }
    #pragma unroll
    for (int n = 0; n < 4; n++)
      #pragma unroll
      for (int r = 0; r < 4; r++)
        p[n][r] = EXP2(p[n][r] - mrow[r]);

    #pragma unroll
    for (int n = 0; n < 4; n++) {
      const int chunk = n*2 + (l15 >> 3);
      #pragma unroll
      for (int r = 0; r < 4; r++) {
        const int prow = g*4 + r;
        sP[wave][prow*64 + ((chunk ^ (prow & 7)) << 3) + x7] = f2bf(p[n][r]);
      }
    }
    asm volatile("s_waitcnt lgkmcnt(0)" ::: "memory");
    __builtin_amdgcn_sched_barrier(0);

    __builtin_amdgcn_s_setprio(1);
    #pragma unroll
    for (int kk = 0; kk < 2; kk++) {
      const int csw = ((kk*4 + g) ^ x7) << 3;
      bf16x8 pa = *(const bf16x8*)&sP[wave][l15*64 + csw];
      #pragma unroll
      for (int nd = 0; nd < 4; nd++) {
        bf16x8 vf = *(const bf16x8*)&sV[cur][(nd*16 + l15)*64 + csw];
        oacc[nd] = __builtin_amdgcn_mfma_f32_16x16x32_bf16(pa, vf, oacc[nd], 0, 0, 0);
      }
      lacc = __builtin_amdgcn_mfma_f32_16x16x32_bf16(pa, ones8, lacc, 0, 0, 0);
    }
    __builtin_amdgcn_s_setprio(0);
  }

  #pragma unroll
  for (int r = 0; r < 4; r++) {
    float inv = RCP(lacc[r]);
    size_t row = (size_t)(b*S_LEN + qrow + g*4 + r);
    #pragma unroll
    for (int nd = 0; nd < 4; nd++)
      ctx[row*DMODEL + h*64 + nd*16 + l15] = f2bf(oacc[nd][r] * inv);
  }
}

// ---------------- host ----------------
extern "C" void kernel_launch(void* const* d_in, const int* in_sizes, int n_in,
                              void* d_out, int out_size, void* d_ws, size_t ws_size,
                              hipStream_t stream)
{
  const float* x    = (const float*)d_in[0];
  const float* Wq   = (const float*)d_in[1];
  const float* Wk   = (const float*)d_in[2];
  const float* Wv   = (const float*)d_in[3];
  const float* Wo   = (const float*)d_in[4];
  const float* bo   = (const float*)d_in[5];
  const float* W1   = (const float*)d_in[6];
  const float* b1   = (const float*)d_in[7];
  const float* W2   = (const float*)d_in[8];
  const float* b2   = (const float*)d_in[9];
  const float* ln1s = (const float*)d_in[10];
  const float* ln1b = (const float*)d_in[11];
  const float* ln2s = (const float*)d_in[12];
  const float* ln2b = (const float*)d_in[13];
  float* out = (float*)d_out;
  (void)in_sizes; (void)n_in; (void)out_size; (void)ws_size;

  char* ws = (char*)d_ws;
  size_t off = 0;
  auto alloc = [&](size_t n) { char* p = ws + off; off += (n + 255) & ~(size_t)255; return p; };
  unsigned short* hbuf  = (unsigned short*)alloc((size_t)NROWS*DMODEL*2);
  unsigned short* qkv   = (unsigned short*)alloc((size_t)NROWS*QKV_LD*2);
  unsigned short* vtb   = (unsigned short*)alloc((size_t)NROWS*DMODEL*2);
  unsigned short* ctx   = (unsigned short*)alloc((size_t)NROWS*DMODEL*2);
  unsigned short* ffn1  = (unsigned short*)alloc((size_t)NROWS*DFF*2);
  unsigned short* wqkvt = (unsigned short*)alloc((size_t)QKV_LD*DMODEL*2);
  unsigned short* wot   = (unsigned short*)alloc((size_t)DMODEL*DMODEL*2);
  unsigned short* w1t   = (unsigned short*)alloc((size_t)DFF*DMODEL*2);
  unsigned short* w2t   = (unsigned short*)alloc((size_t)DMODEL*DFF*2);

  const float SCLQ = 0.18033688011f;  // log2(e)/sqrt(64)

  wtrans_all<<<dim3(3072), dim3(256), 0, stream>>>(
      Wq, Wk, Wv, Wo, W1, W2, wqkvt, wot, w1t, w2t, SCLQ);

  // LN1
  ln_kernel<<<dim3(NROWS), dim3(256), 0, stream>>>(x, ln1s, ln1b, hbuf);
  // fused QKV projection (256x256, BK=32, 2 blocks/CU)
  gemm256b32<false,false><<<dim3(32*12), dim3(512), 0, stream>>>(
      hbuf, wqkvt, qkv, nullptr, NROWS, QKV_LD, DMODEL);
  // V^T
  vtrans<<<dim3(2048), dim3(256), 0, stream>>>(qkv + 2048, vtb);
  // attention (8-wave, QBLK=128)
  attn_kernel<<<dim3(1024), dim3(512), 0, stream>>>(qkv, qkv + 1024, vtb, ctx);
  // out proj + bo + residual(x) -> d_out fp32  (128x256 pipelined, 256 blocks)
  gemm128<true,false,true,true><<<dim3(64*4), dim3(512), 0, stream>>>(
      ctx, wot, (void*)out, bo, x, NROWS, DMODEL, DMODEL);
  // LN2
  ln_kernel<<<dim3(NROWS), dim3(256), 0, stream>>>(out, ln2s, ln2b, hbuf);
  // FFN1 + b1 + GELU -> bf16 (256x256, BK=32, 2 blocks/CU)
  gemm256b32<true,true><<<dim3(32*16), dim3(512), 0, stream>>>(
      hbuf, w1t, ffn1, b1, NROWS, DFF, DMODEL);
  // FFN2 + b2 + residual(d_out) -> d_out fp32  (128x256 pipelined, 256 blocks)
  gemm128<true,false,true,true><<<dim3(64*4), dim3(512), 0, stream>>>(
      ffn1, w2t, (void*)out, b2, out, NROWS, DMODEL, DFF);
}

// Round 13
// 357.525 us; speedup vs baseline: 3.3487x; 3.3487x over previous
//
#include <hip/hip_runtime.h>
#include <math.h>

// ---- problem constants ----
#define S_LEN  2048
#define DMODEL 1024
#define NHEAD  16
#define BATCH  4
#define NROWS  (BATCH*S_LEN)   // 8192
#define DFF    4096
#define QKV_LD 3072            // fused q|k|v row stride

typedef __attribute__((ext_vector_type(4))) unsigned short us4;
typedef __attribute__((ext_vector_type(8))) unsigned short us8;
typedef __attribute__((ext_vector_type(8))) __bf16 bf16x8;
typedef __attribute__((ext_vector_type(4))) float f32x4;

#if __has_builtin(__builtin_amdgcn_exp2f)
#define EXP2(x) __builtin_amdgcn_exp2f(x)
#else
#define EXP2(x) exp2f(x)
#endif
#if __has_builtin(__builtin_amdgcn_rcpf)
#define RCP(x) __builtin_amdgcn_rcpf(x)
#else
#define RCP(x) (1.0f/(x))
#endif

static __device__ __forceinline__ unsigned short f2bf(float f) {
  __bf16 b = (__bf16)f;                       // HW RNE convert on gfx950
  return __builtin_bit_cast(unsigned short, b);
}
#define GLD16(gp, lp) __builtin_amdgcn_global_load_lds( \
    (const __attribute__((address_space(1))) unsigned int*)(gp), \
    (__attribute__((address_space(3))) unsigned int*)(lp), 16, 0, 0)

// XCD-aware bijective block swizzle (requires gridDim.x % 8 == 0)
static __device__ __forceinline__ int xcd_swz(int bid, int nwg) {
  int q = nwg >> 3;
  return (bid & 7) * q + (bid >> 3);
}

// ---------------- LayerNorm: fp32 in -> bf16 out ----------------
__global__ __launch_bounds__(256) void ln_kernel(
    const float* __restrict__ x, const float* __restrict__ scale,
    const float* __restrict__ shift, unsigned short* __restrict__ out)
{
  const int row = blockIdx.x, tid = threadIdx.x;
  const int lane = tid & 63, wave = tid >> 6;
  const float* xr = x + (size_t)row * DMODEL;
  f32x4 v = *(const f32x4*)&xr[tid * 4];
  float s  = v[0]+v[1]+v[2]+v[3];
  float s2 = v[0]*v[0]+v[1]*v[1]+v[2]*v[2]+v[3]*v[3];
  #pragma unroll
  for (int m = 1; m < 64; m <<= 1) { s += __shfl_xor(s, m); s2 += __shfl_xor(s2, m); }
  __shared__ float red[8];
  if (lane == 0) { red[wave] = s; red[4 + wave] = s2; }
  __syncthreads();
  s  = red[0]+red[1]+red[2]+red[3];
  s2 = red[4]+red[5]+red[6]+red[7];
  float mean = s * (1.0f/DMODEL);
  float var  = s2 * (1.0f/DMODEL) - mean*mean;
  float rstd = rsqrtf(var + 1e-5f);
  us4 o;
  #pragma unroll
  for (int j = 0; j < 4; j++) {
    float val = (v[j]-mean)*rstd*scale[tid*4+j] + shift[tid*4+j];
    o[j] = f2bf(val);
  }
  *(us4*)&out[(size_t)row*DMODEL + tid*4] = o;
}

// ------- merged weight convert+transpose: all 6 weights in one launch -------
__global__ __launch_bounds__(256) void wtrans_all(
    const float* __restrict__ Wq, const float* __restrict__ Wk,
    const float* __restrict__ Wv, const float* __restrict__ Wo,
    const float* __restrict__ W1, const float* __restrict__ W2,
    unsigned short* __restrict__ wqkvt, unsigned short* __restrict__ wot,
    unsigned short* __restrict__ w1t, unsigned short* __restrict__ w2t,
    float sclq)
{
  __shared__ unsigned short tile[64][72];
  const int bid = blockIdx.x, tid = threadIdx.x;
  const float* W; unsigned short* Wt; int K, N, sub; float scl = 1.0f;
  if (bid < 1024) {
    int wsel = bid >> 8; sub = bid & 255; K = 1024; N = 1024;
    W  = (wsel == 0) ? Wq : (wsel == 1) ? Wk : (wsel == 2) ? Wv : Wo;
    Wt = (wsel == 0) ? wqkvt : (wsel == 1) ? wqkvt + 1024*1024
       : (wsel == 2) ? wqkvt + 2048*1024 : wot;
    if (wsel == 0) scl = sclq;
  } else if (bid < 2048) { sub = bid - 1024; K = 1024; N = 4096; W = W1; Wt = w1t; }
  else                   { sub = bid - 2048; K = 4096; N = 1024; W = W2; Wt = w2t; }
  const int nbn = N >> 6;
  const int kt = sub / nbn, nt = sub % nbn;
  int r = tid >> 2, c0 = (tid & 3) << 4;
  const float* src = W + (size_t)(kt*64 + r)*N + nt*64 + c0;
  #pragma unroll
  for (int j = 0; j < 16; j += 4) {
    f32x4 f = *(const f32x4*)&src[j];
    tile[r][c0+j+0] = f2bf(f[0]*scl); tile[r][c0+j+1] = f2bf(f[1]*scl);
    tile[r][c0+j+2] = f2bf(f[2]*scl); tile[r][c0+j+3] = f2bf(f[3]*scl);
  }
  __syncthreads();
  int n = tid >> 2, k0 = (tid & 3) << 4;
  us8 o0, o1;
  #pragma unroll
  for (int j = 0; j < 8; j++) { o0[j] = tile[k0+j][n]; o1[j] = tile[k0+8+j][n]; }
  unsigned short* dst = Wt + (size_t)(nt*64 + n)*K + kt*64 + k0;
  *(us8*)&dst[0] = o0;
  *(us8*)&dst[8] = o1;
}

// ------- V transpose: v rows [B*S][QKV_LD] (v section) -> vt[(b*H+h)*64+d][S] -------
__global__ __launch_bounds__(256) void vtrans(
    const unsigned short* __restrict__ v, unsigned short* __restrict__ vt)
{
  __shared__ unsigned short tile[64][72];
  const int tid = threadIdx.x;
  const int bh = blockIdx.x >> 5, st = blockIdx.x & 31;
  const int b = bh >> 4, h = bh & 15;
  int r = tid >> 2, c0 = (tid & 3) << 4;
  const unsigned short* src = v + (size_t)(b*S_LEN + st*64 + r)*QKV_LD + h*64 + c0;
  *(us8*)&tile[r][c0]   = *(const us8*)&src[0];
  *(us8*)&tile[r][c0+8] = *(const us8*)&src[8];
  __syncthreads();
  int d = tid >> 2, s0 = (tid & 3) << 4;
  us8 o0, o1;
  #pragma unroll
  for (int j = 0; j < 8; j++) { o0[j] = tile[s0+j][d]; o1[j] = tile[s0+8+j][d]; }
  unsigned short* dst = vt + (size_t)(bh*64 + d)*S_LEN + st*64 + s0;
  *(us8*)&dst[0] = o0;
  *(us8*)&dst[8] = o1;
}

// ------- 256x256 pipelined GEMM (QKV / FFN1), 4-phase 2-barrier, BK=64 -------
template<bool BIAS, bool GELU_>
__global__ __launch_bounds__(512, 2) void gemm256(
    const unsigned short* __restrict__ A, const unsigned short* __restrict__ Bt,
    unsigned short* __restrict__ Cout, const float* __restrict__ bias,
    int M, int N, int K)
{
  constexpr int BN = 256, WN = 64, NF = 4;
  __shared__ unsigned short sA[2][256*64];
  __shared__ unsigned short sB[2][BN*64];
  const int tid = threadIdx.x;
  const int wave = tid >> 6, lane = tid & 63;
  const int wm = wave >> 2, wn = wave & 3;
  const int l15 = lane & 15, g = lane >> 4, x7 = lane & 7, r8 = lane >> 3;
  const int srcc = (x7 ^ r8) << 3;
  const int nbn = N / BN;
  const int bid = xcd_swz(blockIdx.x, gridDim.x);
  const int bm = bid / nbn, bn = bid % nbn;
  const unsigned short* gA = A  + (size_t)(bm*256)*K;
  const unsigned short* gB = Bt + (size_t)(bn*BN)*K;
  const int NT = K >> 6;

  f32x4 acc[8][NF] = {};

#define STAGEA(buf, h, kb) do { \
    _Pragma("unroll") \
    for (int j_ = 0; j_ < 2; j_++) \
      GLD16(gA + (size_t)((h)*128 + j_*64 + wave*8 + r8)*K + (kb) + srcc, \
            &sA[buf][((h)*128 + j_*64 + wave*8)*64]); \
  } while (0)
#define STAGEB(buf, h, kb) do { \
    _Pragma("unroll") \
    for (int j_ = 0; j_ < 2; j_++) \
      GLD16(gB + (size_t)((h)*128 + j_*64 + wave*8 + r8)*K + (kb) + srcc, \
            &sB[buf][((h)*128 + j_*64 + wave*8)*64]); \
  } while (0)
#define RDA_(m, kk) (*(const bf16x8*)&cA[(wm*128 + (m)*16 + l15)*64 + ((((kk)*4+g)^x7)<<3)])
#define RDB_(n, kk) (*(const bf16x8*)&cB[(wn*WN + (n)*16 + l15)*64 + ((((kk)*4+g)^x7)<<3)])
#define PH(p) do { \
    __builtin_amdgcn_s_setprio(1); \
    _Pragma("unroll") for (int mm_ = 0; mm_ < 2; mm_++) \
    _Pragma("unroll") for (int n_ = 0; n_ < NF; n_++) \
    _Pragma("unroll") for (int kk_ = 0; kk_ < 2; kk_++) \
      acc[(p)*2+mm_][n_] = __builtin_amdgcn_mfma_f32_16x16x32_bf16( \
          af[mm_][kk_], bfr[n_][kk_], acc[(p)*2+mm_][n_], 0, 0, 0); \
    __builtin_amdgcn_s_setprio(0); \
  } while (0)

  // prologue: B(0),A(0) -> buf0 ; B(1) -> buf1
  STAGEB(0, 0, 0); STAGEB(0, 1, 0);
  STAGEA(0, 0, 0); STAGEA(0, 1, 0);
  STAGEB(1, 0, 64); STAGEB(1, 1, 64);

  for (int t = 0; t < NT; ++t) {
    const int c = t & 1;
    const unsigned short* cA = sA[c];
    const unsigned short* cB = sB[c];
    const int kb1 = (t + 1) * 64, kb2 = (t + 2) * 64;
    bf16x8 af[2][2], bfr[NF][2];

    if (t < NT - 1) asm volatile("s_waitcnt vmcnt(4)" ::: "memory");
    else            asm volatile("s_waitcnt vmcnt(0)" ::: "memory");
    __builtin_amdgcn_s_barrier();
    __builtin_amdgcn_sched_barrier(0);

    // ---- ph1: B reg-cache + A m0,m1 ----
    #pragma unroll
    for (int n = 0; n < NF; n++) { bfr[n][0] = RDB_(n, 0); bfr[n][1] = RDB_(n, 1); }
    af[0][0] = RDA_(0, 0); af[0][1] = RDA_(0, 1);
    af[1][0] = RDA_(1, 0); af[1][1] = RDA_(1, 1);
    if (t + 1 < NT) STAGEA(c ^ 1, 0, kb1);
    PH(0);
    // ---- ph2 ----
    af[0][0] = RDA_(2, 0); af[0][1] = RDA_(2, 1);
    af[1][0] = RDA_(3, 0); af[1][1] = RDA_(3, 1);
    if (t + 1 < NT) STAGEA(c ^ 1, 1, kb1);
    PH(1);
    __builtin_amdgcn_s_barrier();        // B-region recycle gate
    // ---- ph3 ----
    af[0][0] = RDA_(4, 0); af[0][1] = RDA_(4, 1);
    af[1][0] = RDA_(5, 0); af[1][1] = RDA_(5, 1);
    if (t + 2 < NT) STAGEB(c, 0, kb2);
    PH(2);
    // ---- ph4 ----
    af[0][0] = RDA_(6, 0); af[0][1] = RDA_(6, 1);
    af[1][0] = RDA_(7, 0); af[1][1] = RDA_(7, 1);
    if (t + 2 < NT) STAGEB(c, 1, kb2);
    PH(3);
  }

  // epilogue
  #pragma unroll
  for (int m = 0; m < 8; m++) {
    #pragma unroll
    for (int r = 0; r < 4; r++) {
      int grow = bm*256 + wm*128 + m*16 + g*4 + r;
      #pragma unroll
      for (int n = 0; n < NF; n++) {
        int gcol = bn*BN + wn*WN + n*16 + l15;
        float v = acc[m][n][r];
        if (BIAS) v += bias[gcol];
        if (GELU_) {
          float xx = v;
          float u = 0.7978845608f*(xx + 0.044715f*xx*xx*xx);
          float e = EXP2(u * 2.88539008f);
          float th = 1.0f - 2.0f*RCP(e + 1.0f);
          v = 0.5f*xx*(1.0f + th);
        }
        Cout[(size_t)grow*N + gcol] = f2bf(v);
      }
    }
  }
#undef STAGEA
#undef STAGEB
#undef RDA_
#undef RDB_
#undef PH
}

// ------- 128x256 pipelined GEMM (Wo / FFN2): 8 waves (2Mx4N), per-wave 64x64 -------
template<bool BIAS, bool GELU_, bool RESID, bool OUTF32>
__global__ __launch_bounds__(512, 2) void gemm128(
    const unsigned short* __restrict__ A, const unsigned short* __restrict__ Bt,
    void* Cout, const float* __restrict__ bias, const float* resid,
    int M, int N, int K)
{
  __shared__ unsigned short sA[2][128*64];
  __shared__ unsigned short sB[2][256*64];
  const int tid = threadIdx.x;
  const int wave = tid >> 6, lane = tid & 63;
  const int wm = wave >> 2, wn = wave & 3;   // 2M x 4N waves
  const int l15 = lane & 15, g = lane >> 4, x7 = lane & 7, r8 = lane >> 3;
  const int srcc = (x7 ^ r8) << 3;
  const int nbn = N >> 8;
  const int bid = xcd_swz(blockIdx.x, gridDim.x);
  const int bm = bid / nbn, bn = bid % nbn;
  const unsigned short* gA = A  + (size_t)(bm*128)*K;
  const unsigned short* gB = Bt + (size_t)(bn*256)*K;
  const int NT = K >> 6;

  f32x4 acc[4][4] = {};

#define STAGEA1(buf, kb) do { \
    _Pragma("unroll") \
    for (int j_ = 0; j_ < 2; j_++) \
      GLD16(gA + (size_t)(j_*64 + wave*8 + r8)*K + (kb) + srcc, \
            &sA[buf][(j_*64 + wave*8)*64]); \
  } while (0)
#define STAGEB1(buf, kb) do { \
    _Pragma("unroll") \
    for (int j_ = 0; j_ < 4; j_++) \
      GLD16(gB + (size_t)(j_*64 + wave*8 + r8)*K + (kb) + srcc, \
            &sB[buf][(j_*64 + wave*8)*64]); \
  } while (0)
#define RDA1(m, kk) (*(const bf16x8*)&cA[(wm*64 + (m)*16 + l15)*64 + ((((kk)*4+g)^x7)<<3)])
#define RDB1(n, kk) (*(const bf16x8*)&cB[(wn*64 + (n)*16 + l15)*64 + ((((kk)*4+g)^x7)<<3)])
#define PH1(p) do { \
    __builtin_amdgcn_s_setprio(1); \
    _Pragma("unroll") for (int mm_ = 0; mm_ < 2; mm_++) \
    _Pragma("unroll") for (int n_ = 0; n_ < 4; n_++) \
    _Pragma("unroll") for (int kk_ = 0; kk_ < 2; kk_++) \
      acc[(p)*2+mm_][n_] = __builtin_amdgcn_mfma_f32_16x16x32_bf16( \
          af[mm_][kk_], bfr[n_][kk_], acc[(p)*2+mm_][n_], 0, 0, 0); \
    __builtin_amdgcn_s_setprio(0); \
  } while (0)

  STAGEB1(0, 0);
  STAGEA1(0, 0);
  STAGEB1(1, 64);

  for (int t = 0; t < NT; ++t) {
    const int c = t & 1;
    const unsigned short* cA = sA[c];
    const unsigned short* cB = sB[c];
    const int kb1 = (t + 1) * 64, kb2 = (t + 2) * 64;
    bf16x8 af[2][2], bfr[4][2];

    if (t < NT - 1) asm volatile("s_waitcnt vmcnt(4)" ::: "memory");
    else            asm volatile("s_waitcnt vmcnt(0)" ::: "memory");
    __builtin_amdgcn_s_barrier();
    __builtin_amdgcn_sched_barrier(0);

    // ---- ph1: B reg-cache + A m0,m1 + stage A(t+1) ----
    #pragma unroll
    for (int n = 0; n < 4; n++) { bfr[n][0] = RDB1(n, 0); bfr[n][1] = RDB1(n, 1); }
    af[0][0] = RDA1(0, 0); af[0][1] = RDA1(0, 1);
    af[1][0] = RDA1(1, 0); af[1][1] = RDA1(1, 1);
    if (t + 1 < NT) STAGEA1(c ^ 1, kb1);
    PH1(0);
    __builtin_amdgcn_s_barrier();        // B-region recycle gate (B reads done)
    // ---- ph2: A m2,m3 + stage B(t+2) into current buf ----
    af[0][0] = RDA1(2, 0); af[0][1] = RDA1(2, 1);
    af[1][0] = RDA1(3, 0); af[1][1] = RDA1(3, 1);
    if (t + 2 < NT) STAGEB1(c, kb2);
    PH1(1);
  }

  #pragma unroll
  for (int m = 0; m < 4; m++) {
    #pragma unroll
    for (int r = 0; r < 4; r++) {
      int grow = bm*128 + wm*64 + m*16 + g*4 + r;
      #pragma unroll
      for (int n = 0; n < 4; n++) {
        int gcol = bn*256 + wn*64 + n*16 + l15;
        float v = acc[m][n][r];
        if (BIAS) v += bias[gcol];
        if (GELU_) {
          float xx = v;
          float u = 0.7978845608f*(xx + 0.044715f*xx*xx*xx);
          float e = EXP2(u * 2.88539008f);
          float th = 1.0f - 2.0f*RCP(e + 1.0f);
          v = 0.5f*xx*(1.0f + th);
        }
        if (RESID) v += resid[(size_t)grow*N + gcol];
        if (OUTF32) ((float*)Cout)[(size_t)grow*N + gcol] = v;
        else ((unsigned short*)Cout)[(size_t)grow*N + gcol] = f2bf(v);
      }
    }
  }
#undef STAGEA1
#undef STAGEB1
#undef RDA1
#undef RDB1
#undef PH1
}

// ---------------- causal flash attention (QBLK=128, proven) ----------------
// 8 waves x 16 q-rows. Ones-column MFMA computes softmax denominator (no sum
// shuffles); max-reduce deferred behind a per-lane ballot (T13). exp2 domain.
__global__ __launch_bounds__(512) void attn_kernel(
    const unsigned short* __restrict__ qb, const unsigned short* __restrict__ kb,
    const unsigned short* __restrict__ vt, unsigned short* __restrict__ ctx)
{
  __shared__ unsigned short sK[2][64*64];
  __shared__ unsigned short sV[2][64*64];
  __shared__ unsigned short sP[8][16*64];
  const int tid = threadIdx.x, wave = tid >> 6, lane = tid & 63;
  const int l15 = lane & 15, g = lane >> 4, x7 = lane & 7;
  const int qt = 15 - (blockIdx.x >> 6);      // heavy-first, QBLK=128
  const int bh = blockIdx.x & 63;
  const int b = bh >> 4, h = bh & 15;
  const int qrow = qt*128 + wave*16;
  const int NTI = 2*qt + 2;                   // KV tiles (64 each)

  bf16x8 qf[2];
  {
    const unsigned short* qr = qb + (size_t)(b*S_LEN + qrow + l15) * QKV_LD + h*64;
    qf[0] = *(const bf16x8*)&qr[g*8];
    qf[1] = *(const bf16x8*)&qr[32 + g*8];
  }

  // all-ones bf16 fragment for the denominator MFMA
  us8 ones_u;
  #pragma unroll
  for (int j = 0; j < 8; j++) ones_u[j] = 0x3F80;
  const bf16x8 ones8 = __builtin_bit_cast(bf16x8, ones_u);

  f32x4 oacc[4] = {};
  f32x4 lacc = {};
  float mrow[4];
  #pragma unroll
  for (int r = 0; r < 4; r++) mrow[r] = -INFINITY;

  const int rrow = lane >> 3;
  const int srcc = (x7 ^ rrow) << 3;
  const unsigned short* kbase = kb + (size_t)(b*S_LEN)*QKV_LD + h*64 + srcc;
  const unsigned short* vbase = vt + (size_t)(bh*64)*S_LEN + srcc;

#define ASTAGE(buf, t) do { \
    const int kv0_ = (t)*64; \
    GLD16(kbase + (size_t)(kv0_ + wave*8 + rrow)*QKV_LD, &sK[buf][wave*8*64]); \
    GLD16(vbase + (size_t)(wave*8 + rrow)*S_LEN + kv0_,  &sV[buf][wave*8*64]); \
  } while(0)

  ASTAGE(0, 0);

  for (int t = 0; t < NTI; ++t) {
    __syncthreads();
    const int cur = t & 1;
    if (t < NTI - 1) ASTAGE(cur ^ 1, t + 1);

    const int kv0 = t*64;
    if (kv0 > qrow + 15) continue;   // fully-masked tile for this wave

    f32x4 sacc[4] = {};
    __builtin_amdgcn_s_setprio(1);
    #pragma unroll
    for (int kk = 0; kk < 2; kk++) {
      const int csw = ((kk*4 + g) ^ x7) << 3;
      #pragma unroll
      for (int n = 0; n < 4; n++) {
        bf16x8 kf = *(const bf16x8*)&sK[cur][(n*16 + l15)*64 + csw];
        sacc[n] = __builtin_amdgcn_mfma_f32_16x16x32_bf16(qf[kk], kf, sacc[n], 0, 0, 0);
      }
    }
    __builtin_amdgcn_s_setprio(0);

    float p[4][4], rm[4];
    const bool masked = (kv0 + 63 > qrow);
    #pragma unroll
    for (int r = 0; r < 4; r++) {
      float m_ = -INFINITY;
      #pragma unroll
      for (int n = 0; n < 4; n++) {
        float sc = sacc[n][r];     // already log2-scaled via Wq
        if (masked && (kv0 + n*16 + l15) > (qrow + g*4 + r)) sc = -INFINITY;
        p[n][r] = sc;
        m_ = fmaxf(m_, sc);
      }
      rm[r] = m_;
    }
    // defer-max: full 16-lane reduce + rescale only when a lane max exceeds
    bool need = (rm[0] > mrow[0] + 8.0f) | (rm[1] > mrow[1] + 8.0f) |
                (rm[2] > mrow[2] + 8.0f) | (rm[3] > mrow[3] + 8.0f);
    if (__any(need)) {
      #pragma unroll
      for (int r = 0; r < 4; r++) {
        float vv = rm[r];
        vv = fmaxf(vv, __shfl_xor(vv, 1));
        vv = fmaxf(vv, __shfl_xor(vv, 2));
        vv = fmaxf(vv, __shfl_xor(vv, 4));
        vv = fmaxf(vv, __shfl_xor(vv, 8));
        float mn = fmaxf(mrow[r], vv);
        float alpha = EXP2(mrow[r] - mn);
        mrow[r] = mn;
        lacc[r] *= alpha;
        #pragma unroll
        for (int nd = 0; nd < 4; nd++) oacc[nd][r] *= alpha;
      }
    }
    #pragma unroll
    for (int n = 0; n < 4; n++)
      #pragma unroll
      for (int r = 0; r < 4; r++)
        p[n][r] = EXP2(p[n][r] - mrow[r]);

    #pragma unroll
    for (int n = 0; n < 4; n++) {
      const int chunk = n*2 + (l15 >> 3);
      #pragma unroll
      for (int r = 0; r < 4; r++) {
        const int prow = g*4 + r;
        sP[wave][prow*64 + ((chunk ^ (prow & 7)) << 3) + x7] = f2bf(p[n][r]);
      }
    }
    asm volatile("s_waitcnt lgkmcnt(0)" ::: "memory");
    __builtin_amdgcn_sched_barrier(0);

    __builtin_amdgcn_s_setprio(1);
    #pragma unroll
    for (int kk = 0; kk < 2; kk++) {
      const int csw = ((kk*4 + g) ^ x7) << 3;
      bf16x8 pa = *(const bf16x8*)&sP[wave][l15*64 + csw];
      #pragma unroll
      for (int nd = 0; nd < 4; nd++) {
        bf16x8 vf = *(const bf16x8*)&sV[cur][(nd*16 + l15)*64 + csw];
        oacc[nd] = __builtin_amdgcn_mfma_f32_16x16x32_bf16(pa, vf, oacc[nd], 0, 0, 0);
      }
      lacc = __builtin_amdgcn_mfma_f32_16x16x32_bf16(pa, ones8, lacc, 0, 0, 0);
    }
    __builtin_amdgcn_s_setprio(0);
  }

  #pragma unroll
  for (int r = 0; r < 4; r++) {
    float inv = RCP(lacc[r]);
    size_t row = (size_t)(b*S_LEN + qrow + g*4 + r);
    #pragma unroll
    for (int nd = 0; nd < 4; nd++)
      ctx[row*DMODEL + h*64 + nd*16 + l15] = f2bf(oacc[nd][r] * inv);
  }
}

// ---------------- host ----------------
extern "C" void kernel_launch(void* const* d_in, const int* in_sizes, int n_in,
                              void* d_out, int out_size, void* d_ws, size_t ws_size,
                              hipStream_t stream)
{
  const float* x    = (const float*)d_in[0];
  const float* Wq   = (const float*)d_in[1];
  const float* Wk   = (const float*)d_in[2];
  const float* Wv   = (const float*)d_in[3];
  const float* Wo   = (const float*)d_in[4];
  const float* bo   = (const float*)d_in[5];
  const float* W1   = (const float*)d_in[6];
  const float* b1   = (const float*)d_in[7];
  const float* W2   = (const float*)d_in[8];
  const float* b2   = (const float*)d_in[9];
  const float* ln1s = (const float*)d_in[10];
  const float* ln1b = (const float*)d_in[11];
  const float* ln2s = (const float*)d_in[12];
  const float* ln2b = (const float*)d_in[13];
  float* out = (float*)d_out;
  (void)in_sizes; (void)n_in; (void)out_size; (void)ws_size;

  char* ws = (char*)d_ws;
  size_t off = 0;
  auto alloc = [&](size_t n) { char* p = ws + off; off += (n + 255) & ~(size_t)255; return p; };
  unsigned short* hbuf  = (unsigned short*)alloc((size_t)NROWS*DMODEL*2);
  unsigned short* qkv   = (unsigned short*)alloc((size_t)NROWS*QKV_LD*2);
  unsigned short* vtb   = (unsigned short*)alloc((size_t)NROWS*DMODEL*2);
  unsigned short* ctx   = (unsigned short*)alloc((size_t)NROWS*DMODEL*2);
  unsigned short* ffn1  = (unsigned short*)alloc((size_t)NROWS*DFF*2);
  unsigned short* wqkvt = (unsigned short*)alloc((size_t)QKV_LD*DMODEL*2);
  unsigned short* wot   = (unsigned short*)alloc((size_t)DMODEL*DMODEL*2);
  unsigned short* w1t   = (unsigned short*)alloc((size_t)DFF*DMODEL*2);
  unsigned short* w2t   = (unsigned short*)alloc((size_t)DMODEL*DFF*2);

  const float SCLQ = 0.18033688011f;  // log2(e)/sqrt(64)

  wtrans_all<<<dim3(3072), dim3(256), 0, stream>>>(
      Wq, Wk, Wv, Wo, W1, W2, wqkvt, wot, w1t, w2t, SCLQ);

  // LN1
  ln_kernel<<<dim3(NROWS), dim3(256), 0, stream>>>(x, ln1s, ln1b, hbuf);
  // fused QKV projection (256x256 pipelined)
  gemm256<false,false><<<dim3(32*12), dim3(512), 0, stream>>>(
      hbuf, wqkvt, qkv, nullptr, NROWS, QKV_LD, DMODEL);
  // V^T
  vtrans<<<dim3(2048), dim3(256), 0, stream>>>(qkv + 2048, vtb);
  // attention (8-wave, QBLK=128)
  attn_kernel<<<dim3(1024), dim3(512), 0, stream>>>(qkv, qkv + 1024, vtb, ctx);
  // out proj + bo + residual(x) -> d_out fp32  (128x256 pipelined, 256 blocks)
  gemm128<true,false,true,true><<<dim3(64*4), dim3(512), 0, stream>>>(
      ctx, wot, (void*)out, bo, x, NROWS, DMODEL, DMODEL);
  // LN2
  ln_kernel<<<dim3(NROWS), dim3(256), 0, stream>>>(out, ln2s, ln2b, hbuf);
  // FFN1 + b1 + GELU -> bf16 (256x256 pipelined)
  gemm256<true,true><<<dim3(32*16), dim3(512), 0, stream>>>(
      hbuf, w1t, ffn1, b1, NROWS, DFF, DMODEL);
  // FFN2 + b2 + residual(d_out) -> d_out fp32  (128x256 pipelined, 256 blocks)
  gemm128<true,false,true,true><<<dim3(64*4), dim3(512), 0, stream>>>(
      ffn1, w2t, (void*)out, b2, out, NROWS, DMODEL, DFF);
}